// Round 3
// baseline (357.393 us; speedup 1.0000x reference)
//
#include <hip/hip_runtime.h>
#include <hip/hip_bf16.h>
#include <stdint.h>

#define T_SEQ 336
#define P_LEN 720
#define C_LEN 1782
#define NB    64
#define NKT   11        // K-steps of 32 (336 -> 352, tail masked/zero-padded)
#define PT_T  6         // p tiles of 128 (720 -> 768, zero-padded in Apack)
#define CT_T  14        // c tiles of 128 (1782 -> 1792, masked)

typedef __attribute__((ext_vector_type(4))) float f32x4;
typedef __attribute__((ext_vector_type(8))) short s16x8;

__device__ __forceinline__ unsigned short f2bf(float f) {
  unsigned int u = __builtin_bit_cast(unsigned int, f);
  u += 0x7FFFu + ((u >> 16) & 1u);   // RNE
  return (unsigned short)(u >> 16);
}

// Weff[p,k] = Ws[p,k] + 0.2*sum_{t in win(k)} (Wt-Ws)[p,t], written directly in
// MFMA A-fragment order: block (pt*8+r16)*11+kt holds 64 lanes x 16B, where
// lane = lg*16 + l16 carries W[p0+r16*16+l16][kt*32+lg*8+j], j=0..7.
__global__ __launch_bounds__(64) void prep_w(
    const float* __restrict__ Ws, const float* __restrict__ bs,
    const float* __restrict__ Wt, const float* __restrict__ bt,
    unsigned short* __restrict__ apack, float* __restrict__ bias) {
  const int p   = blockIdx.x;          // 0..767
  const int tid = threadIdx.x;         // 0..63
  if (tid < NKT * 4) {
    const int kt = tid >> 2;
    const int lg = tid & 3;
    const float* wsr = Ws + (size_t)p * T_SEQ;
    const float* wtr = Wt + (size_t)p * T_SEQ;
    union { s16x8 v; unsigned short u[8]; } pk;
#pragma unroll
    for (int j = 0; j < 8; ++j) {
      const int k = kt * 32 + lg * 8 + j;
      float val = 0.f;
      if (p < P_LEN && k < T_SEQ) {
        float d;
        if (k == 0) {
          d = 3.f*(wtr[0]-wsr[0]) + 2.f*(wtr[1]-wsr[1]) + (wtr[2]-wsr[2]);
        } else if (k == T_SEQ-1) {
          d = 3.f*(wtr[T_SEQ-1]-wsr[T_SEQ-1]) + 2.f*(wtr[T_SEQ-2]-wsr[T_SEQ-2])
              + (wtr[T_SEQ-3]-wsr[T_SEQ-3]);
        } else {
          int lo = (k-2 < 0) ? 0 : k-2;
          int hi = (k+2 > T_SEQ-1) ? T_SEQ-1 : k+2;
          d = 0.f;
          for (int t = lo; t <= hi; ++t) d += wtr[t]-wsr[t];
        }
        val = wsr[k] + 0.2f*d;
      }
      pk.u[j] = f2bf(val);
    }
    const int pt  = p >> 7;
    const int r16 = (p >> 4) & 7;
    const int l16 = p & 15;
    const int blk = (pt * 8 + r16) * NKT + kt;
    *(s16x8*)&apack[(size_t)(blk * 64 + lg * 16 + l16) * 8] = pk.v;
  }
  if (tid == 0 && p < P_LEN) bias[p] = bs[p] + bt[p];
}

// O[b,p,c] = relu( sum_k Weff[p,k] * X[b,k,c] + bias[p] )
// Barrier-free, LDS-free: A-frags from packed Weff (1 coalesced dwordx4/lane),
// B-frags straight from fp32 x (8 predicated dwords + cvt_pk). 4 independent
// waves per block, each owns a 64x64 output tile.
__global__ __launch_bounds__(256, 3) void gemm_kernel(
    const float* __restrict__ x, const unsigned short* __restrict__ apack,
    const float* __restrict__ bias, float* __restrict__ out) {
  // XCD swizzle: each XCD gets 8 consecutive b; within XCD, p-tiles fastest
  const int bid = blockIdx.x;
  const int w   = (bid & 7) * 672 + (bid >> 3);   // 5376 = 8*672
  const int b   = w / 84;                         // 84 = CT_T*PT_T
  const int rem = w % 84;
  const int ct  = rem / PT_T;
  const int pt  = rem % PT_T;
  const int p0  = pt * 128;
  const int c0  = ct * 128;

  const int tid  = threadIdx.x;
  const int lane = tid & 63;
  const int wid  = tid >> 6;
  const int wp   = wid >> 1;
  const int wc   = wid & 1;
  const int l16  = lane & 15;
  const int lg   = lane >> 4;

  const float* xb = x + (size_t)b * T_SEQ * C_LEN;
  const s16x8* ap = (const s16x8*)apack;

  int  cn[4];
  bool cm[4];
#pragma unroll
  for (int n = 0; n < 4; ++n) {
    cn[n] = c0 + wc * 64 + n * 16 + l16;
    cm[n] = cn[n] < C_LEN;
  }

  f32x4 acc[4][4] = {};

  for (int kt = 0; kt < NKT; ++kt) {
    // A fragments: one coalesced 16B load per lane per m
    s16x8 af[4];
#pragma unroll
    for (int m = 0; m < 4; ++m)
      af[m] = ap[(size_t)(((pt * 8 + wp * 4 + m) * NKT + kt) * 64 + lane)];

    // B fragments: 8 fp32 loads (uniform predicate per group) + cvt_pk
    const int  k0  = kt * 32 + lg * 8;
    const bool kok = (kt < NKT - 1) || (lg < 2);   // kt=10: only k=320..335 valid
    s16x8 bf_[4];
#pragma unroll
    for (int n = 0; n < 4; ++n) {
      const bool ok = kok && cm[n];
      float f[8];
#pragma unroll
      for (int j = 0; j < 8; ++j)
        f[j] = ok ? xb[(size_t)(k0 + j) * C_LEN + cn[n]] : 0.f;
      union { s16x8 v; uint32_t dw[4]; } bu;
#pragma unroll
      for (int h = 0; h < 4; ++h) {
        uint32_t r;
        asm("v_cvt_pk_bf16_f32 %0, %1, %2" : "=v"(r) : "v"(f[2*h]), "v"(f[2*h+1]));
        bu.dw[h] = r;
      }
      bf_[n] = bu.v;
    }

#pragma unroll
    for (int m = 0; m < 4; ++m)
#pragma unroll
      for (int n = 0; n < 4; ++n)
        acc[m][n] = __builtin_amdgcn_mfma_f32_16x16x32_bf16(
            af[m], bf_[n], acc[m][n], 0, 0, 0);
  }

  // epilogue: bias + relu + masked store. C/D layout: row = lg*4 + r, col = l16
  const size_t ob = (size_t)b * P_LEN * C_LEN;
#pragma unroll
  for (int m = 0; m < 4; ++m) {
    const int pb0 = p0 + wp * 64 + m * 16 + lg * 4;
    float bv[4];
#pragma unroll
    for (int r = 0; r < 4; ++r)
      bv[r] = (pb0 + r < P_LEN) ? bias[pb0 + r] : 0.f;
#pragma unroll
    for (int n = 0; n < 4; ++n) {
      const int cc = c0 + wc * 64 + n * 16 + l16;
      if (cc < C_LEN) {
#pragma unroll
        for (int r = 0; r < 4; ++r) {
          if (pb0 + r < P_LEN) {
            float vv = acc[m][n][r] + bv[r];
            out[ob + (size_t)(pb0 + r) * C_LEN + cc] = fmaxf(vv, 0.f);
          }
        }
      }
    }
  }
}

extern "C" void kernel_launch(void* const* d_in, const int* in_sizes, int n_in,
                              void* d_out, int out_size, void* d_ws, size_t ws_size,
                              hipStream_t stream) {
  (void)in_sizes; (void)n_in; (void)out_size; (void)ws_size;
  const float* x  = (const float*)d_in[0];
  const float* Ws = (const float*)d_in[1];
  const float* bs = (const float*)d_in[2];
  const float* Wt = (const float*)d_in[3];
  const float* bt = (const float*)d_in[4];
  float* out = (float*)d_out;

  // ws: Apack (6*8*11 blocks * 1KB = 540672 B) then bias (720 f32)
  unsigned short* apack = (unsigned short*)d_ws;
  float* bias = (float*)((char*)d_ws + (size_t)PT_T * 8 * NKT * 1024);

  prep_w<<<dim3(768), dim3(64), 0, stream>>>(Ws, bs, Wt, bt, apack, bias);
  gemm_kernel<<<dim3(NB * CT_T * PT_T), dim3(256), 0, stream>>>(x, apack, bias, out);
}